// Round 5
// baseline (204.487 us; speedup 1.0000x reference)
//
#include <hip/hip_runtime.h>

// Window attention, fused, 32KB-LDS version. Head-split phase 1; Q,K,P MFMA
// fragments built IN-REGISTER via ds_bpermute reorg (no LDS round-trip);
// only x-stage, K (same-wave), V^T (transpose), O (cross-head) touch LDS.
// R0 16KB: x -> V^T.  R1 16KB: K -> O.  4 barriers.
// B=4096, N=49, C=128, H=4, d=32. MFMA 16x16x32 bf16. 4+ blocks/CU.

#define N_TOK 49
#define R1B 16384

typedef __attribute__((ext_vector_type(8))) __bf16 bf16x8;
typedef __attribute__((ext_vector_type(4))) __bf16 bf16x4;
typedef __attribute__((ext_vector_type(4))) float  f32x4;

// ---- weight pre-pack: WqkvT A-frags (49152 bf16) + Wproj B-frags (16384 bf16)
__global__ void pack_weights(const float* __restrict__ Wqkv,
                             const float* __restrict__ Wproj,
                             __bf16* __restrict__ ws) {
    int idx  = blockIdx.x * 256 + threadIdx.x;   // 65536 total
    int j    = idx & 7;
    int lane = (idx >> 3) & 63;
    int l16  = lane & 15, g = lane >> 4;
    if (idx < 49152) {
        int frag = idx >> 9;
        int mt = frag >> 2, ks = frag & 3;
        int m = mt * 16 + l16;            // outch
        int k = ks * 32 + g * 8 + j;      // inch
        ws[idx] = (__bf16)Wqkv[k * 384 + m];
    } else {
        int i2 = idx - 49152;
        int frag = i2 >> 9;
        int nt = frag >> 2, ks = frag & 3;
        int n = nt * 16 + l16;            // outch
        int k = ks * 32 + g * 8 + j;      // inch
        ws[idx] = (__bf16)Wproj[k * 128 + n];
    }
}

// LDS offsets (byte), XOR-swizzled on the 16B-block index.
__device__ __forceinline__ int x_off(int tok, int ch) {          // R0, 256B rows
    return tok * 256 + ((((ch >> 3) ^ (tok & 15))) << 4) + ((ch & 7) << 1);
}
__device__ __forceinline__ int vt_off(int h, int ch, int tok) {  // R0, 128B rows
    return h * 4096 + ch * 128 + ((((tok >> 3) ^ (ch & 7))) << 4) + ((tok & 7) << 1);
}
__device__ __forceinline__ int k_off(int h, int tok, int ch) {   // R1, 64B rows
    return R1B + h * 4096 + tok * 64 + ((((ch >> 3) ^ (tok & 3))) << 4) + ((ch & 7) << 1);
}
__device__ __forceinline__ int o_off(int tok, int ch) {          // R1, 256B rows
    return R1B + tok * 256 + ((((ch >> 3) ^ (tok & 15))) << 4) + ((ch & 7) << 1);
}

__device__ __forceinline__ int pk2(float a, float b) {
    union { __bf16 h[2]; int u; } U;
    U.h[0] = (__bf16)a; U.h[1] = (__bf16)b;
    return U.u;
}

// D-layout -> A/B-frag-layout reorg (movement only along g = lane>>4).
// Inputs: per source lane (l16,g_src): m0w0={c0,c1}, m0w1={c2,c3} of m-pair lo
// (c = 4*g_src+i), m1w* of m-pair hi. Output lane (l16,g): 8 consecutive
// k-elems 8g..8g+7 taken from m-pair (g>=2), source g_src = 2(g&1)(+1).
__device__ __forceinline__ bf16x8 reorg8(int m0w0, int m0w1, int m1w0, int m1w1,
                                         int lane) {
    int aA = ((lane & 15) | ((lane & 16) << 1)) << 2;   // (l16 + 32*(g&1))*4
    int aB = aA + 64;                                   // +16 lanes
    int A0 = __builtin_amdgcn_ds_bpermute(aA, m0w0);
    int A1 = __builtin_amdgcn_ds_bpermute(aA, m0w1);
    int B0 = __builtin_amdgcn_ds_bpermute(aB, m0w0);
    int B1 = __builtin_amdgcn_ds_bpermute(aB, m0w1);
    int C0 = __builtin_amdgcn_ds_bpermute(aA, m1w0);
    int C1 = __builtin_amdgcn_ds_bpermute(aA, m1w1);
    int D0 = __builtin_amdgcn_ds_bpermute(aB, m1w0);
    int D1 = __builtin_amdgcn_ds_bpermute(aB, m1w1);
    bool hi = lane >= 32;
    union { int u[4]; bf16x8 v; } U;
    U.u[0] = hi ? C0 : A0;
    U.u[1] = hi ? C1 : A1;
    U.u[2] = hi ? D0 : B0;
    U.u[3] = hi ? D1 : B1;
    return U.v;
}

__global__ __launch_bounds__(256, 4)
void fused_win_attn(const float* __restrict__ x,
                    const float* __restrict__ bqkv,
                    const float* __restrict__ bproj,
                    const __bf16* __restrict__ wpack,
                    float* __restrict__ out) {
    __shared__ __align__(16) char smem[32768];

    const int tid  = threadIdx.x;
    const int w    = tid >> 6;       // head (ph1-2) / och-tile pair (ph3)
    const int lane = tid & 63;
    const int l16  = lane & 15;
    const int g    = lane >> 4;
    const int b    = blockIdx.x;
    const float* xb = x + (size_t)b * (N_TOK * 128);

    // ===== Phase 0: x (fp32 HBM) -> bf16 swizzled LDS; rows 49..63 zeroed ====
    #pragma unroll
    for (int it = 0; it < 4; ++it) {
        int unit = tid + it * 256;        // 1024 units of 8 ch
        int tok = unit >> 4, ch = (unit & 15) * 8;
        f32x4 lo = {0.f, 0.f, 0.f, 0.f}, hi = {0.f, 0.f, 0.f, 0.f};
        if (tok < N_TOK) {
            const float* p = xb + tok * 128 + ch;
            lo = *(const f32x4*)p;
            hi = *(const f32x4*)(p + 4);
        }
        bf16x8 f;
        f[0]=(__bf16)lo[0]; f[1]=(__bf16)lo[1]; f[2]=(__bf16)lo[2]; f[3]=(__bf16)lo[3];
        f[4]=(__bf16)hi[0]; f[5]=(__bf16)hi[1]; f[6]=(__bf16)hi[2]; f[7]=(__bf16)hi[3];
        *(bf16x8*)(smem + x_off(tok, ch)) = f;
    }
    __syncthreads();   // B1: x staged

    // ===== Phase 1: head w's 96 channels (Q,K,V) x 64 tokens, K=128 =========
    f32x4 acc[6][4];
    #pragma unroll
    for (int m = 0; m < 6; ++m)
        #pragma unroll
        for (int nt = 0; nt < 4; ++nt) acc[m][nt] = (f32x4){0.f, 0.f, 0.f, 0.f};

    #pragma unroll
    for (int ks = 0; ks < 4; ++ks) {
        bf16x8 xfr[4];
        #pragma unroll
        for (int nt = 0; nt < 4; ++nt)
            xfr[nt] = *(const bf16x8*)(smem + x_off(16 * nt + l16, 32 * ks + 8 * g));
        #pragma unroll
        for (int m = 0; m < 6; ++m) {
            int mtg = (m < 2) ? (2 * w + m) : (m < 4) ? (8 + 2 * w + m - 2)
                                                      : (16 + 2 * w + m - 4);
            bf16x8 af = *(const bf16x8*)(wpack + ((mtg * 4 + ks) * 64 + lane) * 8);
            #pragma unroll
            for (int nt = 0; nt < 4; ++nt)
                acc[m][nt] = __builtin_amdgcn_mfma_f32_16x16x32_bf16(af, xfr[nt], acc[m][nt], 0, 0, 0);
        }
    }

    // --- K (m=2,3) -> LDS R1 (written+read by this wave only) ---------------
    #pragma unroll
    for (int m = 2; m < 4; ++m) {
        const int lch = 16 * (m - 2) + 4 * g;
        f32x4 bias = *(const f32x4*)(bqkv + 128 + 32 * w + lch);
        #pragma unroll
        for (int nt = 0; nt < 4; ++nt) {
            bf16x4 pk = {(__bf16)(acc[m][nt][0] + bias[0]), (__bf16)(acc[m][nt][1] + bias[1]),
                         (__bf16)(acc[m][nt][2] + bias[2]), (__bf16)(acc[m][nt][3] + bias[3])};
            *(bf16x4*)(smem + k_off(w, 16 * nt + l16, lch)) = pk;
        }
    }
    // --- Q (m=0,1) -> qf in-register reorg ----------------------------------
    f32x4 bq0 = *(const f32x4*)(bqkv + 32 * w + 0 + 4 * g);
    f32x4 bq1 = *(const f32x4*)(bqkv + 32 * w + 16 + 4 * g);
    bf16x8 qf[4];
    #pragma unroll
    for (int t = 0; t < 4; ++t) {
        int m0w0 = pk2(acc[0][t][0] + bq0[0], acc[0][t][1] + bq0[1]);
        int m0w1 = pk2(acc[0][t][2] + bq0[2], acc[0][t][3] + bq0[3]);
        int m1w0 = pk2(acc[1][t][0] + bq1[0], acc[1][t][1] + bq1[1]);
        int m1w1 = pk2(acc[1][t][2] + bq1[2], acc[1][t][3] + bq1[3]);
        qf[t] = reorg8(m0w0, m0w1, m1w0, m1w1, lane);
    }
    __syncthreads();   // B2: all x reads done -> R0 becomes V^T

    // --- V (m=4,5) -> V^T in R0 (scalar transpose writes; same-wave reads) --
    #pragma unroll
    for (int m = 4; m < 6; ++m) {
        const int vch = 16 * (m - 4) + 4 * g;
        f32x4 bias = *(const f32x4*)(bqkv + 256 + 32 * w + vch);
        #pragma unroll
        for (int nt = 0; nt < 4; ++nt) {
            const int T = 16 * nt + l16;
            *(__bf16*)(smem + vt_off(w, vch + 0, T)) = (__bf16)(acc[m][nt][0] + bias[0]);
            *(__bf16*)(smem + vt_off(w, vch + 1, T)) = (__bf16)(acc[m][nt][1] + bias[1]);
            *(__bf16*)(smem + vt_off(w, vch + 2, T)) = (__bf16)(acc[m][nt][2] + bias[2]);
            *(__bf16*)(smem + vt_off(w, vch + 3, T)) = (__bf16)(acc[m][nt][3] + bias[3]);
        }
    }

    // ===== Phase 2a: S^T = K_h @ Q_h^T (M=64 keys, N=64 q, K=32 ch) =========
    bf16x8 kf[4];
    #pragma unroll
    for (int t = 0; t < 4; ++t)
        kf[t] = *(const bf16x8*)(smem + k_off(w, 16 * t + l16, 8 * g));
    f32x4 s[4][4];
    #pragma unroll
    for (int mt = 0; mt < 4; ++mt)
        #pragma unroll
        for (int nt = 0; nt < 4; ++nt)
            s[mt][nt] = __builtin_amdgcn_mfma_f32_16x16x32_bf16(
                kf[mt], qf[nt], (f32x4){0.f, 0.f, 0.f, 0.f}, 0, 0, 0);

    // softmax over keys, NO max-subtract (|S*SC| small; exp2 safe), unnormalized
    // P; normalization folded into O. Lane holds keys {16mt+4g+i}, q=16nt+l16.
    constexpr float SC = 0.08838834764831845f * 1.4426950408889634f;  // scale*log2e
    float r[4];
    #pragma unroll
    for (int nt = 0; nt < 4; ++nt) {
        float sum = 0.f;
        #pragma unroll
        for (int mt = 0; mt < 4; ++mt)
            #pragma unroll
            for (int i = 0; i < 4; ++i) {
                int key = 16 * mt + 4 * g + i;
                float p = (key < N_TOK) ? __builtin_amdgcn_exp2f(s[mt][nt][i] * SC) : 0.f;
                s[mt][nt][i] = p;
                sum += p;
            }
        sum += __shfl_xor(sum, 16);
        sum += __shfl_xor(sum, 32);
        r[nt] = __builtin_amdgcn_rcpf(sum);
    }

    // --- P -> pf in-register reorg (same pattern; m-pair = (2ks, 2ks+1)) ----
    bf16x8 pf[4][2];
    #pragma unroll
    for (int nt = 0; nt < 4; ++nt)
        #pragma unroll
        for (int ks = 0; ks < 2; ++ks) {
            int m0w0 = pk2(s[2 * ks][nt][0], s[2 * ks][nt][1]);
            int m0w1 = pk2(s[2 * ks][nt][2], s[2 * ks][nt][3]);
            int m1w0 = pk2(s[2 * ks + 1][nt][0], s[2 * ks + 1][nt][1]);
            int m1w1 = pk2(s[2 * ks + 1][nt][2], s[2 * ks + 1][nt][3]);
            pf[nt][ks] = reorg8(m0w0, m0w1, m1w0, m1w1, lane);
        }

    // ===== Phase 2b: O^T = V_h^T @ P^T (M=32 ch, N=64 q, K=64 keys) =========
    bf16x8 vf[2][2];
    #pragma unroll
    for (int ks = 0; ks < 2; ++ks)
        #pragma unroll
        for (int m = 0; m < 2; ++m)
            vf[m][ks] = *(const bf16x8*)(smem + vt_off(w, 16 * m + l16, 32 * ks + 8 * g));
    f32x4 o[2][4];
    #pragma unroll
    for (int m = 0; m < 2; ++m)
        #pragma unroll
        for (int nt = 0; nt < 4; ++nt) o[m][nt] = (f32x4){0.f, 0.f, 0.f, 0.f};
    #pragma unroll
    for (int ks = 0; ks < 2; ++ks)
        #pragma unroll
        for (int m = 0; m < 2; ++m)
            #pragma unroll
            for (int nt = 0; nt < 4; ++nt)
                o[m][nt] = __builtin_amdgcn_mfma_f32_16x16x32_bf16(
                    vf[m][ks], pf[nt][ks], o[m][nt], 0, 0, 0);
    __syncthreads();   // B3: all waves' K reads done -> R1 becomes O

    // O[tok][ch] (normalized) -> R1; lane: q=16nt+l16, ch=32w+16m+4g+i
    #pragma unroll
    for (int m = 0; m < 2; ++m)
        #pragma unroll
        for (int nt = 0; nt < 4; ++nt) {
            bf16x4 pk = {(__bf16)(o[m][nt][0] * r[nt]), (__bf16)(o[m][nt][1] * r[nt]),
                         (__bf16)(o[m][nt][2] * r[nt]), (__bf16)(o[m][nt][3] * r[nt])};
            *(bf16x4*)(smem + o_off(16 * nt + l16, 32 * w + 16 * m + 4 * g)) = pk;
        }
    __syncthreads();   // B4: O complete

    // ===== Phase 3: out = O @ Wproj + bproj; wave w owns och 32w..32w+31 ====
    const __bf16* bp = wpack + 49152;
    bf16x8 bpf[2][4];
    #pragma unroll
    for (int ntp = 0; ntp < 2; ++ntp)
        #pragma unroll
        for (int ks = 0; ks < 4; ++ks)
            bpf[ntp][ks] = *(const bf16x8*)(bp + (((2 * w + ntp) * 4 + ks) * 64 + lane) * 8);
    f32x4 po[4][2];
    #pragma unroll
    for (int mt = 0; mt < 4; ++mt) {
        po[mt][0] = (f32x4){0.f, 0.f, 0.f, 0.f};
        po[mt][1] = (f32x4){0.f, 0.f, 0.f, 0.f};
    }
    #pragma unroll
    for (int ks = 0; ks < 4; ++ks) {
        #pragma unroll
        for (int mt = 0; mt < 4; ++mt) {
            bf16x8 a = *(const bf16x8*)(smem + o_off(16 * mt + l16, 32 * ks + 8 * g));
            po[mt][0] = __builtin_amdgcn_mfma_f32_16x16x32_bf16(a, bpf[0][ks], po[mt][0], 0, 0, 0);
            po[mt][1] = __builtin_amdgcn_mfma_f32_16x16x32_bf16(a, bpf[1][ks], po[mt][1], 0, 0, 0);
        }
    }
    #pragma unroll
    for (int ntp = 0; ntp < 2; ++ntp) {
        const int och = 16 * (2 * w + ntp) + l16;
        const float bias = bproj[och];
        #pragma unroll
        for (int mt = 0; mt < 4; ++mt)
            #pragma unroll
            for (int i = 0; i < 4; ++i) {
                int tok = 16 * mt + 4 * g + i;
                if (tok < N_TOK)
                    out[((size_t)b * N_TOK + tok) * 128 + och] = po[mt][ntp][i] + bias;
            }
    }
}

extern "C" void kernel_launch(void* const* d_in, const int* in_sizes, int n_in,
                              void* d_out, int out_size, void* d_ws, size_t ws_size,
                              hipStream_t stream) {
    const float* x     = (const float*)d_in[0];
    const float* Wqkv  = (const float*)d_in[1];
    const float* bqkv  = (const float*)d_in[2];
    const float* Wproj = (const float*)d_in[3];
    const float* bproj = (const float*)d_in[4];
    __bf16* ws  = (__bf16*)d_ws;
    float* outp = (float*)d_out;

    pack_weights<<<256, 256, 0, stream>>>(Wqkv, Wproj, ws);
    fused_win_attn<<<4096, 256, 0, stream>>>(x, bqkv, bproj, ws, outp);
}

// Round 6
// 80.245 us; speedup vs baseline: 2.5483x; 2.5483x over previous
//
#include <hip/hip_runtime.h>

// Window attention, fused, 32KB-LDS, register-budgeted (<128 VGPR, 4 waves/EU).
// Phase 1 head-split in TWO passes (Q+K then V) to cap live accumulators.
// Q/P MFMA fragments built in-register via ds_bpermute reorg; K via same-wave
// LDS; V^T via LDS transpose; O via LDS for cross-head proj. 4 barriers.
// R0 16KB: x -> V^T.  R1 16KB: K -> O.
// B=4096, N=49, C=128, H=4, d=32. MFMA 16x16x32 bf16.

#define N_TOK 49
#define R1B 16384

typedef __attribute__((ext_vector_type(8))) __bf16 bf16x8;
typedef __attribute__((ext_vector_type(4))) __bf16 bf16x4;
typedef __attribute__((ext_vector_type(4))) float  f32x4;

// ---- weight pre-pack: WqkvT A-frags (49152 bf16) + Wproj B-frags (16384 bf16)
__global__ void pack_weights(const float* __restrict__ Wqkv,
                             const float* __restrict__ Wproj,
                             __bf16* __restrict__ ws) {
    int idx  = blockIdx.x * 256 + threadIdx.x;   // 65536 total
    int j    = idx & 7;
    int lane = (idx >> 3) & 63;
    int l16  = lane & 15, g = lane >> 4;
    if (idx < 49152) {
        int frag = idx >> 9;
        int mt = frag >> 2, ks = frag & 3;
        int m = mt * 16 + l16;            // outch
        int k = ks * 32 + g * 8 + j;      // inch
        ws[idx] = (__bf16)Wqkv[k * 384 + m];
    } else {
        int i2 = idx - 49152;
        int frag = i2 >> 9;
        int nt = frag >> 2, ks = frag & 3;
        int n = nt * 16 + l16;            // outch
        int k = ks * 32 + g * 8 + j;      // inch
        ws[idx] = (__bf16)Wproj[k * 128 + n];
    }
}

// LDS offsets (byte), XOR-swizzled on the 16B-block index.
__device__ __forceinline__ int x_off(int tok, int ch) {          // R0, 256B rows
    return tok * 256 + ((((ch >> 3) ^ (tok & 15))) << 4) + ((ch & 7) << 1);
}
__device__ __forceinline__ int vt_off(int h, int ch, int tok) {  // R0, 128B rows
    return h * 4096 + ch * 128 + ((((tok >> 3) ^ (ch & 7))) << 4) + ((tok & 7) << 1);
}
__device__ __forceinline__ int k_off(int h, int tok, int ch) {   // R1, 64B rows
    return R1B + h * 4096 + tok * 64 + ((((ch >> 3) ^ (tok & 3))) << 4) + ((ch & 7) << 1);
}
__device__ __forceinline__ int o_off(int tok, int ch) {          // R1, 256B rows
    return R1B + tok * 256 + ((((ch >> 3) ^ (tok & 15))) << 4) + ((ch & 7) << 1);
}

__device__ __forceinline__ int pk2(float a, float b) {
    union { __bf16 h[2]; int u; } U;
    U.h[0] = (__bf16)a; U.h[1] = (__bf16)b;
    return U.u;
}

// D-layout -> A/B-frag-layout reorg (movement only along g = lane>>4).
__device__ __forceinline__ bf16x8 reorg8(int m0w0, int m0w1, int m1w0, int m1w1,
                                         int lane) {
    int aA = ((lane & 15) | ((lane & 16) << 1)) << 2;   // (l16 + 32*(g&1))*4
    int aB = aA + 64;                                   // +16 lanes
    int A0 = __builtin_amdgcn_ds_bpermute(aA, m0w0);
    int A1 = __builtin_amdgcn_ds_bpermute(aA, m0w1);
    int B0 = __builtin_amdgcn_ds_bpermute(aB, m0w0);
    int B1 = __builtin_amdgcn_ds_bpermute(aB, m0w1);
    int C0 = __builtin_amdgcn_ds_bpermute(aA, m1w0);
    int C1 = __builtin_amdgcn_ds_bpermute(aA, m1w1);
    int D0 = __builtin_amdgcn_ds_bpermute(aB, m1w0);
    int D1 = __builtin_amdgcn_ds_bpermute(aB, m1w1);
    bool hi = lane >= 32;
    union { int u[4]; bf16x8 v; } U;
    U.u[0] = hi ? C0 : A0;
    U.u[1] = hi ? C1 : A1;
    U.u[2] = hi ? D0 : B0;
    U.u[3] = hi ? D1 : B1;
    return U.v;
}

__global__ __launch_bounds__(256, 4)
void fused_win_attn(const float* __restrict__ x,
                    const float* __restrict__ bqkv,
                    const float* __restrict__ bproj,
                    const __bf16* __restrict__ wpack,
                    float* __restrict__ out) {
    __shared__ __align__(16) char smem[32768];

    const int tid  = threadIdx.x;
    const int w    = tid >> 6;       // head (ph1-2) / och-tile pair (ph3)
    const int lane = tid & 63;
    const int l16  = lane & 15;
    const int g    = lane >> 4;
    const int b    = blockIdx.x;
    const float* xb = x + (size_t)b * (N_TOK * 128);

    // ===== Phase 0: x (fp32 HBM) -> bf16 swizzled LDS; rows 49..63 zeroed ====
    #pragma unroll
    for (int it = 0; it < 4; ++it) {
        int unit = tid + it * 256;        // 1024 units of 8 ch
        int tok = unit >> 4, ch = (unit & 15) * 8;
        f32x4 lo = {0.f, 0.f, 0.f, 0.f}, hi = {0.f, 0.f, 0.f, 0.f};
        if (tok < N_TOK) {
            const float* p = xb + tok * 128 + ch;
            lo = *(const f32x4*)p;
            hi = *(const f32x4*)(p + 4);
        }
        bf16x8 f;
        f[0]=(__bf16)lo[0]; f[1]=(__bf16)lo[1]; f[2]=(__bf16)lo[2]; f[3]=(__bf16)lo[3];
        f[4]=(__bf16)hi[0]; f[5]=(__bf16)hi[1]; f[6]=(__bf16)hi[2]; f[7]=(__bf16)hi[3];
        *(bf16x8*)(smem + x_off(tok, ch)) = f;
    }
    __syncthreads();   // B1: x staged

    // ===== Phase 1 pass A: head w's Q,K (4 m-tiles), K=128 ==================
    f32x4 accA[4][4];
    #pragma unroll
    for (int m = 0; m < 4; ++m)
        #pragma unroll
        for (int nt = 0; nt < 4; ++nt) accA[m][nt] = (f32x4){0.f, 0.f, 0.f, 0.f};
    #pragma unroll
    for (int ks = 0; ks < 4; ++ks) {
        bf16x8 xfr[4];
        #pragma unroll
        for (int nt = 0; nt < 4; ++nt)
            xfr[nt] = *(const bf16x8*)(smem + x_off(16 * nt + l16, 32 * ks + 8 * g));
        #pragma unroll
        for (int m = 0; m < 4; ++m) {
            int mtg = (m < 2) ? (2 * w + m) : (8 + 2 * w + m - 2);
            bf16x8 af = *(const bf16x8*)(wpack + ((mtg * 4 + ks) * 64 + lane) * 8);
            #pragma unroll
            for (int nt = 0; nt < 4; ++nt)
                accA[m][nt] = __builtin_amdgcn_mfma_f32_16x16x32_bf16(af, xfr[nt], accA[m][nt], 0, 0, 0);
        }
    }
    // K (m=2,3) -> LDS R1 (written+read by this wave only)
    #pragma unroll
    for (int m = 2; m < 4; ++m) {
        const int lch = 16 * (m - 2) + 4 * g;
        f32x4 bias = *(const f32x4*)(bqkv + 128 + 32 * w + lch);
        #pragma unroll
        for (int nt = 0; nt < 4; ++nt) {
            bf16x4 pk = {(__bf16)(accA[m][nt][0] + bias[0]), (__bf16)(accA[m][nt][1] + bias[1]),
                         (__bf16)(accA[m][nt][2] + bias[2]), (__bf16)(accA[m][nt][3] + bias[3])};
            *(bf16x4*)(smem + k_off(w, 16 * nt + l16, lch)) = pk;
        }
    }
    // Q (m=0,1) -> qf in-register reorg
    f32x4 bq0 = *(const f32x4*)(bqkv + 32 * w + 0 + 4 * g);
    f32x4 bq1 = *(const f32x4*)(bqkv + 32 * w + 16 + 4 * g);
    bf16x8 qf[4];
    #pragma unroll
    for (int t = 0; t < 4; ++t) {
        int m0w0 = pk2(accA[0][t][0] + bq0[0], accA[0][t][1] + bq0[1]);
        int m0w1 = pk2(accA[0][t][2] + bq0[2], accA[0][t][3] + bq0[3]);
        int m1w0 = pk2(accA[1][t][0] + bq1[0], accA[1][t][1] + bq1[1]);
        int m1w1 = pk2(accA[1][t][2] + bq1[2], accA[1][t][3] + bq1[3]);
        qf[t] = reorg8(m0w0, m0w1, m1w0, m1w1, lane);
    }

    // ===== Phase 1 pass B: head w's V (2 m-tiles) ============================
    f32x4 accB[2][4];
    #pragma unroll
    for (int m = 0; m < 2; ++m)
        #pragma unroll
        for (int nt = 0; nt < 4; ++nt) accB[m][nt] = (f32x4){0.f, 0.f, 0.f, 0.f};
    #pragma unroll
    for (int ks = 0; ks < 4; ++ks) {
        bf16x8 xfr[4];
        #pragma unroll
        for (int nt = 0; nt < 4; ++nt)
            xfr[nt] = *(const bf16x8*)(smem + x_off(16 * nt + l16, 32 * ks + 8 * g));
        #pragma unroll
        for (int m = 0; m < 2; ++m) {
            bf16x8 af = *(const bf16x8*)(wpack + (((16 + 2 * w + m) * 4 + ks) * 64 + lane) * 8);
            #pragma unroll
            for (int nt = 0; nt < 4; ++nt)
                accB[m][nt] = __builtin_amdgcn_mfma_f32_16x16x32_bf16(af, xfr[nt], accB[m][nt], 0, 0, 0);
        }
    }
    __syncthreads();   // B2: all x reads done -> R0 becomes V^T

    // V -> V^T in R0 (scalar transpose writes; same-wave reads); accB dies here
    #pragma unroll
    for (int m = 0; m < 2; ++m) {
        const int vch = 16 * m + 4 * g;
        f32x4 bias = *(const f32x4*)(bqkv + 256 + 32 * w + vch);
        #pragma unroll
        for (int nt = 0; nt < 4; ++nt) {
            const int T = 16 * nt + l16;
            *(__bf16*)(smem + vt_off(w, vch + 0, T)) = (__bf16)(accB[m][nt][0] + bias[0]);
            *(__bf16*)(smem + vt_off(w, vch + 1, T)) = (__bf16)(accB[m][nt][1] + bias[1]);
            *(__bf16*)(smem + vt_off(w, vch + 2, T)) = (__bf16)(accB[m][nt][2] + bias[2]);
            *(__bf16*)(smem + vt_off(w, vch + 3, T)) = (__bf16)(accB[m][nt][3] + bias[3]);
        }
    }

    // ===== Phase 2a: S^T = K_h @ Q_h^T (M=64 keys, N=64 q, K=32 ch) =========
    bf16x8 kf[4];
    #pragma unroll
    for (int t = 0; t < 4; ++t)
        kf[t] = *(const bf16x8*)(smem + k_off(w, 16 * t + l16, 8 * g));
    f32x4 s[4][4];
    #pragma unroll
    for (int mt = 0; mt < 4; ++mt)
        #pragma unroll
        for (int nt = 0; nt < 4; ++nt)
            s[mt][nt] = __builtin_amdgcn_mfma_f32_16x16x32_bf16(
                kf[mt], qf[nt], (f32x4){0.f, 0.f, 0.f, 0.f}, 0, 0, 0);

    // softmax over keys, no max-subtract (|S*SC| small), unnormalized P;
    // normalization folded into O. Lane holds keys {16mt+4g+i}, q=16nt+l16.
    constexpr float SC = 0.08838834764831845f * 1.4426950408889634f;  // scale*log2e
    float r[4];
    #pragma unroll
    for (int nt = 0; nt < 4; ++nt) {
        float sum = 0.f;
        #pragma unroll
        for (int mt = 0; mt < 4; ++mt)
            #pragma unroll
            for (int i = 0; i < 4; ++i) {
                int key = 16 * mt + 4 * g + i;
                float p = (key < N_TOK) ? __builtin_amdgcn_exp2f(s[mt][nt][i] * SC) : 0.f;
                s[mt][nt][i] = p;
                sum += p;
            }
        sum += __shfl_xor(sum, 16);
        sum += __shfl_xor(sum, 32);
        r[nt] = __builtin_amdgcn_rcpf(sum);
    }

    // P -> pf in-register reorg (m-pair = (2ks, 2ks+1)); s dies progressively
    bf16x8 pf[4][2];
    #pragma unroll
    for (int nt = 0; nt < 4; ++nt)
        #pragma unroll
        for (int ks = 0; ks < 2; ++ks) {
            int m0w0 = pk2(s[2 * ks][nt][0], s[2 * ks][nt][1]);
            int m0w1 = pk2(s[2 * ks][nt][2], s[2 * ks][nt][3]);
            int m1w0 = pk2(s[2 * ks + 1][nt][0], s[2 * ks + 1][nt][1]);
            int m1w1 = pk2(s[2 * ks + 1][nt][2], s[2 * ks + 1][nt][3]);
            pf[nt][ks] = reorg8(m0w0, m0w1, m1w0, m1w1, lane);
        }

    // ===== Phase 2b: O^T = V_h^T @ P^T (M=32 ch, N=64 q, K=64 keys) =========
    bf16x8 vf[2][2];
    #pragma unroll
    for (int ks = 0; ks < 2; ++ks)
        #pragma unroll
        for (int m = 0; m < 2; ++m)
            vf[m][ks] = *(const bf16x8*)(smem + vt_off(w, 16 * m + l16, 32 * ks + 8 * g));
    f32x4 o[2][4];
    #pragma unroll
    for (int m = 0; m < 2; ++m)
        #pragma unroll
        for (int nt = 0; nt < 4; ++nt) o[m][nt] = (f32x4){0.f, 0.f, 0.f, 0.f};
    #pragma unroll
    for (int ks = 0; ks < 2; ++ks)
        #pragma unroll
        for (int m = 0; m < 2; ++m)
            #pragma unroll
            for (int nt = 0; nt < 4; ++nt)
                o[m][nt] = __builtin_amdgcn_mfma_f32_16x16x32_bf16(
                    vf[m][ks], pf[nt][ks], o[m][nt], 0, 0, 0);

    // prefetch proj B-frags (L2 latency hides under barrier + O writes)
    const __bf16* bp = wpack + 49152;
    bf16x8 bpf[2][4];
    #pragma unroll
    for (int ntp = 0; ntp < 2; ++ntp)
        #pragma unroll
        for (int ks = 0; ks < 4; ++ks)
            bpf[ntp][ks] = *(const bf16x8*)(bp + (((2 * w + ntp) * 4 + ks) * 64 + lane) * 8);
    __syncthreads();   // B3: all waves' K reads done -> R1 becomes O

    // O[tok][ch] (normalized) -> R1; lane: q=16nt+l16, ch=32w+16m+4g+i
    #pragma unroll
    for (int m = 0; m < 2; ++m)
        #pragma unroll
        for (int nt = 0; nt < 4; ++nt) {
            bf16x4 pk = {(__bf16)(o[m][nt][0] * r[nt]), (__bf16)(o[m][nt][1] * r[nt]),
                         (__bf16)(o[m][nt][2] * r[nt]), (__bf16)(o[m][nt][3] * r[nt])};
            *(bf16x4*)(smem + o_off(16 * nt + l16, 32 * w + 16 * m + 4 * g)) = pk;
        }
    __syncthreads();   // B4: O complete

    // ===== Phase 3: out = O @ Wproj + bproj; wave w owns och 32w..32w+31 ====
    f32x4 po[4][2];
    #pragma unroll
    for (int mt = 0; mt < 4; ++mt) {
        po[mt][0] = (f32x4){0.f, 0.f, 0.f, 0.f};
        po[mt][1] = (f32x4){0.f, 0.f, 0.f, 0.f};
    }
    #pragma unroll
    for (int ks = 0; ks < 4; ++ks) {
        #pragma unroll
        for (int mt = 0; mt < 4; ++mt) {
            bf16x8 a = *(const bf16x8*)(smem + o_off(16 * mt + l16, 32 * ks + 8 * g));
            po[mt][0] = __builtin_amdgcn_mfma_f32_16x16x32_bf16(a, bpf[0][ks], po[mt][0], 0, 0, 0);
            po[mt][1] = __builtin_amdgcn_mfma_f32_16x16x32_bf16(a, bpf[1][ks], po[mt][1], 0, 0, 0);
        }
    }
    #pragma unroll
    for (int ntp = 0; ntp < 2; ++ntp) {
        const int och = 16 * (2 * w + ntp) + l16;
        const float bias = bproj[och];
        #pragma unroll
        for (int mt = 0; mt < 4; ++mt)
            #pragma unroll
            for (int i = 0; i < 4; ++i) {
                int tok = 16 * mt + 4 * g + i;
                if (tok < N_TOK)
                    out[((size_t)b * N_TOK + tok) * 128 + och] = po[mt][ntp][i] + bias;
            }
    }
}

extern "C" void kernel_launch(void* const* d_in, const int* in_sizes, int n_in,
                              void* d_out, int out_size, void* d_ws, size_t ws_size,
                              hipStream_t stream) {
    const float* x     = (const float*)d_in[0];
    const float* Wqkv  = (const float*)d_in[1];
    const float* bqkv  = (const float*)d_in[2];
    const float* Wproj = (const float*)d_in[3];
    const float* bproj = (const float*)d_in[4];
    __bf16* ws  = (__bf16*)d_ws;
    float* outp = (float*)d_out;

    pack_weights<<<256, 256, 0, stream>>>(Wqkv, Wproj, ws);
    fused_win_attn<<<4096, 256, 0, stream>>>(x, bqkv, bproj, ws, outp);
}